// Round 1
// baseline (374.751 us; speedup 1.0000x reference)
//
#include <hip/hip_runtime.h>
#include <math.h>

#define DM    1024
#define DH    64
#define NCTX  4096

// workspace layout (float offsets)
#define WS_Q   0
#define WS_K   (NCTX*DH)
#define WS_U   (2*NCTX*DH)
#define WS_Y   (3*NCTX*DH)
#define WS_WK  (4*NCTX*DH)   // transposed W_k [DM][DH]

// ---------------- W_kT -> Wk transpose ----------------
__global__ __launch_bounds__(256) void wk_transpose_kernel(
    const float* __restrict__ WkT, float* __restrict__ Wk)
{
  int tg = blockIdx.x * 256 + threadIdx.x;   // 0..65535
  int m = tg >> 6, h = tg & 63;
  Wk[tg] = WkT[h * DM + m];                  // Wk[m][h] = WkT[h][m]
}

// ---------------- projections: Q = x@Wq, K = x@Wk, U = x@Wo ----------------
// grid (64 row-tiles, 6 = 3 mats x 2 col-halves), block 128 (2 waves).
// lane = row, wave covers 16 cols via wave-uniform scalar W loads.
__global__ __launch_bounds__(128) void proj_kernel(
    const float* __restrict__ x, const float* __restrict__ Wq,
    const float* __restrict__ Wk, const float* __restrict__ Wo,
    float* __restrict__ Q, float* __restrict__ Kc, float* __restrict__ U)
{
  __shared__ float xs[32][68];
  const int tid  = threadIdx.x;
  const int lane = tid & 63;
  const int w    = __builtin_amdgcn_readfirstlane(tid >> 6);
  const int r0   = blockIdx.x * 64;
  const int mat  = blockIdx.y >> 1;
  const int ch   = blockIdx.y & 1;
  const int h0   = ch * 32 + w * 16;
  const float* Wmat = (mat == 0) ? Wq : (mat == 1) ? Wk : Wo;
  float* Out        = (mat == 0) ? Q  : (mat == 1) ? Kc : U;

  float acc[16];
  #pragma unroll
  for (int j = 0; j < 16; ++j) acc[j] = 0.f;

  for (int kt = 0; kt < DM; kt += 32) {
    __syncthreads();
    #pragma unroll
    for (int it = 0; it < 4; ++it) {
      int idx = it * 128 + tid;            // 0..511  (64 rows x 8 float4)
      int r = idx >> 3, c4 = idx & 7;
      float4 v = *(const float4*)&x[(r0 + r) * DM + kt + c4 * 4];
      xs[c4*4+0][r] = v.x; xs[c4*4+1][r] = v.y;
      xs[c4*4+2][r] = v.z; xs[c4*4+3][r] = v.w;
    }
    __syncthreads();
    #pragma unroll
    for (int kk = 0; kk < 32; ++kk) {
      float a = xs[kk][lane];
      const float4* wr = (const float4*)&Wmat[(kt + kk) * DH + h0]; // uniform -> s_load
      float4 w0 = wr[0], w1 = wr[1], w2 = wr[2], w3 = wr[3];
      acc[0]  += a * w0.x;  acc[1]  += a * w0.y;
      acc[2]  += a * w0.z;  acc[3]  += a * w0.w;
      acc[4]  += a * w1.x;  acc[5]  += a * w1.y;
      acc[6]  += a * w1.z;  acc[7]  += a * w1.w;
      acc[8]  += a * w2.x;  acc[9]  += a * w2.y;
      acc[10] += a * w2.z;  acc[11] += a * w2.w;
      acc[12] += a * w3.x;  acc[13] += a * w3.y;
      acc[14] += a * w3.z;  acc[15] += a * w3.w;
    }
  }
  #pragma unroll
  for (int j = 0; j < 16; ++j)
    Out[(r0 + lane) * DH + h0 + j] = acc[j];
}

// ---------------- flash attention (causal, no scale), f32 ----------------
__device__ __forceinline__ float wave_reduce_max(float v) {
  #pragma unroll
  for (int off = 32; off > 0; off >>= 1)
    v = fmaxf(v, __shfl_xor(v, off, 64));
  return v;
}
__device__ __forceinline__ float wave_reduce_sum(float v) {
  #pragma unroll
  for (int off = 32; off > 0; off >>= 1)
    v += __shfl_xor(v, off, 64);
  return v;
}

// grid 1024 (4 query rows per block, one row per wave), block 256.
__global__ __launch_bounds__(256) void attn_kernel(
    const float* __restrict__ Q, const float* __restrict__ Kc,
    const float* __restrict__ U, float* __restrict__ Y)
{
  __shared__ float Kt[64][68];    // K tile [key][dim], padded
  __shared__ float UtT[64][68];   // U tile transposed [dim][key], padded
  __shared__ float ps[4][64];     // per-wave p vector
  __shared__ float qs[4][64];     // staging for q rows

  const int tid  = threadIdx.x;
  const int lane = tid & 63;
  const int w    = __builtin_amdgcn_readfirstlane(tid >> 6);
  const int r_base = 4 * (gridDim.x - 1 - blockIdx.x);  // heaviest first
  const int r = r_base + w;

  qs[tid >> 6][tid & 63] = Q[(r_base + (tid >> 6)) * DH + (tid & 63)];
  __syncthreads();
  float4 q4[16];
  #pragma unroll
  for (int i = 0; i < 16; ++i) q4[i] = *(const float4*)&qs[w][i * 4];

  float m = -INFINITY, l = 0.f, acc = 0.f;
  const int nt = (r_base >> 6) + 1;

  for (int t = 0; t < nt; ++t) {
    const int j0 = t * 64;
    __syncthreads();
    #pragma unroll
    for (int it = 0; it < 4; ++it) {
      int idx = it * 256 + tid;          // 0..1023 (64 keys x 16 float4)
      int jj = idx >> 4, d4 = idx & 15;
      float4 kv = *(const float4*)&Kc[(j0 + jj) * DH + d4 * 4];
      *(float4*)&Kt[jj][d4 * 4] = kv;
      float4 uv = *(const float4*)&U[(j0 + jj) * DH + d4 * 4];
      UtT[d4*4+0][jj] = uv.x; UtT[d4*4+1][jj] = uv.y;
      UtT[d4*4+2][jj] = uv.z; UtT[d4*4+3][jj] = uv.w;
    }
    __syncthreads();

    // scores: lane = key j0+lane
    float s = -3.0e38f;
    if (j0 + lane <= r) {
      float sv = 0.f;
      #pragma unroll
      for (int i = 0; i < 16; ++i) {
        float4 k4 = *(const float4*)&Kt[lane][i * 4];
        sv += q4[i].x * k4.x + q4[i].y * k4.y + q4[i].z * k4.z + q4[i].w * k4.w;
      }
      s = sv;
    }
    // online softmax
    float tmax  = wave_reduce_max(s);
    float m_new = fmaxf(m, tmax);
    float p = (j0 + lane <= r) ? __expf(s - m_new) : 0.f;
    float tsum  = wave_reduce_sum(p);
    float scale = __expf(m - m_new);     // first tile: exp(-inf) = 0
    l = l * scale + tsum;
    acc *= scale;
    ps[w][lane] = p;                     // wave-private; lgkmcnt ordering by compiler
    // PV: lane = output dim d
    #pragma unroll
    for (int i = 0; i < 16; ++i) {
      float4 p4 = *(const float4*)&ps[w][i * 4];
      float4 u4 = *(const float4*)&UtT[lane][i * 4];
      acc += p4.x * u4.x + p4.y * u4.y + p4.z * u4.z + p4.w * u4.w;
    }
    m = m_new;
  }
  Y[r * DH + lane] = acc / l;
}

// ---------------- epilogue: out = Y @ W_vT  ([4096,64]@[64,1024]) ----------------
// grid (64 row-tiles, 4 col-tiles of 256), block 256.
__global__ __launch_bounds__(256) void out_kernel(
    const float* __restrict__ Y, const float* __restrict__ Wv,
    float* __restrict__ out)
{
  __shared__ float Ws[64][256];   // Wv tile [h][c], no pad needed (h uniform in reads)
  __shared__ float YsT[64][64];   // Y tile transposed [h][row]
  const int tid = threadIdx.x;
  const int r0  = blockIdx.x * 64;
  const int cb  = blockIdx.y;           // 0..3
  const int c4  = tid & 63;
  const int rg  = __builtin_amdgcn_readfirstlane(tid >> 6);  // 0..3

  #pragma unroll
  for (int it = 0; it < 16; ++it) {
    int idx = it * 256 + tid;           // 0..4095
    int h = idx >> 6, cc = idx & 63;
    *(float4*)&Ws[h][cc * 4] = *(const float4*)&Wv[h * DM + cb * 256 + cc * 4];
  }
  #pragma unroll
  for (int it = 0; it < 4; ++it) {
    int idx = it * 256 + tid;           // 0..1023
    int h4 = idx & 15, rr = idx >> 4;
    float4 yv = *(const float4*)&Y[(r0 + rr) * DH + h4 * 4];
    YsT[h4*4+0][rr] = yv.x; YsT[h4*4+1][rr] = yv.y;
    YsT[h4*4+2][rr] = yv.z; YsT[h4*4+3][rr] = yv.w;
  }
  __syncthreads();

  float4 acc[16];
  #pragma unroll
  for (int i = 0; i < 16; ++i) acc[i] = make_float4(0.f, 0.f, 0.f, 0.f);

  #pragma unroll 8
  for (int h = 0; h < 64; ++h) {
    float4 w4 = *(const float4*)&Ws[h][c4 * 4];
    #pragma unroll
    for (int g = 0; g < 4; ++g) {
      float4 y4 = *(const float4*)&YsT[h][rg * 16 + g * 4];  // broadcast
      float ys[4] = {y4.x, y4.y, y4.z, y4.w};
      #pragma unroll
      for (int e = 0; e < 4; ++e) {
        acc[g*4+e].x += ys[e] * w4.x;
        acc[g*4+e].y += ys[e] * w4.y;
        acc[g*4+e].z += ys[e] * w4.z;
        acc[g*4+e].w += ys[e] * w4.w;
      }
    }
  }
  #pragma unroll
  for (int i = 0; i < 16; ++i)
    *(float4*)&out[(r0 + rg * 16 + i) * DM + cb * 256 + c4 * 4] = acc[i];
}

extern "C" void kernel_launch(void* const* d_in, const int* in_sizes, int n_in,
                              void* d_out, int out_size, void* d_ws, size_t ws_size,
                              hipStream_t stream) {
  const float* x   = (const float*)d_in[0];
  const float* Wq  = (const float*)d_in[1];
  const float* WkT = (const float*)d_in[2];
  const float* Wo  = (const float*)d_in[3];
  const float* Wv  = (const float*)d_in[4];
  float* out = (float*)d_out;
  float* ws  = (float*)d_ws;
  float* Q   = ws + WS_Q;
  float* Kc  = ws + WS_K;
  float* U   = ws + WS_U;
  float* Y   = ws + WS_Y;
  float* Wk  = ws + WS_WK;

  hipLaunchKernelGGL(wk_transpose_kernel, dim3(256), dim3(256), 0, stream, WkT, Wk);
  hipLaunchKernelGGL(proj_kernel, dim3(64, 6), dim3(128), 0, stream,
                     x, Wq, Wk, Wo, Q, Kc, U);
  hipLaunchKernelGGL(attn_kernel, dim3(1024), dim3(256), 0, stream, Q, Kc, U, Y);
  hipLaunchKernelGGL(out_kernel, dim3(64, 4), dim3(256), 0, stream, Y, Wv, out);
}